// Round 1
// 1246.382 us; speedup vs baseline: 1.2366x; 1.2366x over previous
//
#include <hip/hip_runtime.h>
#include <cstdint>

typedef __attribute__((ext_vector_type(8))) short short8;
typedef __attribute__((ext_vector_type(4))) float floatx4;
typedef unsigned int uint32;

typedef const void __attribute__((address_space(1)))* gcptr;
typedef void __attribute__((address_space(3)))* lptr;

// ---------------- problem dims ----------------
constexpr int Bn = 8, Sn = 1024, Dn = 1024, Hn = 4096;
constexpr uint32 KTOP = 1024u * 1024u;   // min(TOP_K*S, S*H) = 2^20
constexpr uint32 SKBASE = 0xBB000000u;   // skey of +2^-9
constexpr uint32 EMAX = (1u << 27) - 1u;
constexpr uint32 WLO = 3645;             // bucket of 0.28
constexpr uint32 WHI = 4157;             // bucket of 0.56
constexpr uint32 CAP = 1u << 20;         // per-batch buffer capacity (8*CAP*4 = 32 MiB)

// ---------------- workspace layout (bytes) ----------------
constexpr size_t NX  = (size_t)Bn * Sn * Dn;   // 8388608
constexpr size_t NW1 = (size_t)Hn * Dn;        // 4194304
constexpr size_t NW2 = (size_t)Hn * Hn;        // 16777216
constexpr size_t NRS = (size_t)Bn * Sn * Hn;   // 33554432

constexpr size_t OFF_XH   = 0;
constexpr size_t OFF_XL   = OFF_XH  + 2 * NX;
constexpr size_t OFF_W1H  = OFF_XL  + 2 * NX;
constexpr size_t OFF_W1L  = OFF_W1H + 2 * NW1;
constexpr size_t OFF_W2H  = OFF_W1L + 2 * NW1;
constexpr size_t OFF_W2L  = OFF_W2H + 2 * NW2;
constexpr size_t OFF_RSH  = OFF_W2L + 2 * NW2;
constexpr size_t OFF_RSL  = OFF_RSH + 2 * NRS;
constexpr size_t OFF_HIST = OFF_RSL + 2 * NRS;
constexpr size_t OFF_HIST2= OFF_HIST + (size_t)Bn * 8192 * 4;
constexpr size_t OFF_HMAX = OFF_HIST2+ (size_t)Bn * 16384 * 4;
constexpr size_t OFF_META = OFF_HMAX + (size_t)Bn * Hn * 4;
constexpr size_t OFF_BSEL = OFF_META + 4096;
constexpr size_t OFF_MASK = OFF_BSEL + (size_t)Bn * Hn * 4;
constexpr size_t WS_SMALL = OFF_MASK + (size_t)Bn * Hn * 4;
constexpr size_t ZERO_BYTES = OFF_BSEL - OFF_HIST;
constexpr size_t OFF_BUF  = OFF_XL;

// ---------------- helpers ----------------
__device__ __forceinline__ ushort f2bf(float f) {        // fp32 -> bf16 RNE
  uint32 u = __float_as_uint(f);
  u += 0x7fffu + ((u >> 16) & 1u);
  return (ushort)(u >> 16);
}
__device__ __forceinline__ float bf2f(ushort h) {
  return __uint_as_float(((uint32)h) << 16);
}
__device__ __forceinline__ uint32 skey(float v) {        // monotone fp32 -> u32 key
  uint32 u = __float_as_uint(v);
  return (u & 0x80000000u) ? ~u : (u | 0x80000000u);
}
__device__ __forceinline__ uint32 ekey(uint32 key) {     // 27-bit compact key
  if (key <= SKBASE) return 0u;
  uint32 d = key - SKBASE;
  return d > EMAX ? EMAX : d;
}
__device__ __forceinline__ void g2l(const ushort* src, ushort* dst) {
  __builtin_amdgcn_global_load_lds((gcptr)src, (lptr)dst, 16, 0, 0);
}
// 128x32 staging for the legacy 128^2 kernel (G3/G4)
__device__ __forceinline__ void stage_tile(ushort* lds, const ushort* gbase, int ldg, int tid) {
  const int w = tid >> 6;
  const int c0 = tid, c1 = tid + 256;
  g2l(gbase + (size_t)(c0 >> 2) * ldg + (c0 & 3) * 8, lds + (size_t)(w * 64) * 8);
  g2l(gbase + (size_t)(c1 >> 2) * ldg + (c1 & 3) * 8, lds + (size_t)(256 + w * 64) * 8);
}
__device__ __forceinline__ void stage_tile_sel(ushort* lds, const ushort* upw,
                                               const ushort* modw, const uint32* bm,
                                               int n0, int k0, int ldg, int tid) {
  const int w = tid >> 6;
  const int c0 = tid, c1 = tid + 256;
  const int r0 = n0 + (c0 >> 2), r1 = n0 + (c1 >> 2);
  const ushort* s0 = (bm[r0] ? modw : upw) + (size_t)r0 * ldg + k0 + (c0 & 3) * 8;
  const ushort* s1 = (bm[r1] ? modw : upw) + (size_t)r1 * ldg + k0 + (c1 & 3) * 8;
  g2l(s0, lds + (size_t)(w * 64) * 8);
  g2l(s1, lds + (size_t)(256 + w * 64) * 8);
}

// ---------------- conversion kernels ----------------
__global__ __launch_bounds__(256) void cvt_split_k(const float4* __restrict__ x,
                                                   ushort* __restrict__ hi,
                                                   ushort* __restrict__ lo, int n4) {
  int stride = gridDim.x * 256;
  for (int i = blockIdx.x * 256 + threadIdx.x; i < n4; i += stride) {
    float4 v = x[i];
    ushort h0 = f2bf(v.x), h1 = f2bf(v.y), h2 = f2bf(v.z), h3 = f2bf(v.w);
    ushort4 hv; hv.x = h0; hv.y = h1; hv.z = h2; hv.w = h3;
    *(ushort4*)(hi + (size_t)i * 4) = hv;
    ushort4 lv;
    lv.x = f2bf(v.x - bf2f(h0)); lv.y = f2bf(v.y - bf2f(h1));
    lv.z = f2bf(v.z - bf2f(h2)); lv.w = f2bf(v.w - bf2f(h3));
    *(ushort4*)(lo + (size_t)i * 4) = lv;
  }
}
__global__ __launch_bounds__(256) void cvt_single_k(const float4* __restrict__ x,
                                                    ushort* __restrict__ hi, int n4) {
  int stride = gridDim.x * 256;
  for (int i = blockIdx.x * 256 + threadIdx.x; i < n4; i += stride) {
    float4 v = x[i];
    ushort4 hv; hv.x = f2bf(v.x); hv.y = f2bf(v.y); hv.z = f2bf(v.z); hv.w = f2bf(v.w);
    *(ushort4*)(hi + (size_t)i * 4) = hv;
  }
}
__global__ __launch_bounds__(256) void zero_out_k(float* __restrict__ o, int n) {
  int i = blockIdx.x * 256 + threadIdx.x;
  if (i < n) o[i] = 0.f;
}

// ---------------- epilogue ids ----------------
constexpr int EPI_RELU = 0;    // out: rs_hi/rs_lo bf16 split of relu(acc+bias[n])
constexpr int EPI_SCORE = 1;   // hist/colmax + windowed key append of acc+bias[n]
constexpr int EPI_SILU = 2;    // out: bf16 silu(acc+bias[n]), batched via blockIdx.z
constexpr int EPI_F32 = 3;     // out: f32 acc+bias[n]

// ================= legacy 128^2 GEMM (kept for G3/G4) =================
template <bool SPLIT, bool SELB, int EPI>
__global__ __launch_bounds__(256, SPLIT ? 3 : 2) void gemm_bt(
    const ushort* __restrict__ Ah, const ushort* __restrict__ Al,
    const ushort* __restrict__ Bh, const ushort* __restrict__ Bl,
    const uint32* __restrict__ bmask,
    int N, int K, long long a_bs, long long o_bs, long long bias_bs,
    const float* __restrict__ bias,
    void* __restrict__ outp, void* __restrict__ out2p,
    uint32* __restrict__ hist, uint32* __restrict__ hmax,
    uint32* __restrict__ buf, uint32* __restrict__ cnt) {
  __shared__ __align__(16) ushort lds[SPLIT ? 16384 : 8192];
  ushort* As = lds;
  ushort* Bs = lds + (SPLIT ? 8192 : 4096);

  const int tid = threadIdx.x;
  const int w = tid >> 6, l = tid & 63;
  const int wm = (w >> 1) << 6, wn = (w & 1) << 6;
  const int lm = l & 15, lq = l >> 4;
  const int m0 = blockIdx.y << 7, n0 = blockIdx.x << 7;
  const int z = blockIdx.z;

  const ushort* pAh = Ah + (size_t)z * a_bs + (size_t)m0 * K;
  const ushort* pAl = SPLIT ? Al + (size_t)z * a_bs + (size_t)m0 * K : nullptr;
  const ushort* pBh = SELB ? nullptr : Bh + (size_t)n0 * K;
  const ushort* pBl = (SPLIT && !SELB) ? Bl + (size_t)n0 * K : nullptr;
  const uint32* bm = SELB ? bmask + (size_t)z * Hn : nullptr;

  floatx4 acc[4][4];
#pragma unroll
  for (int i = 0; i < 4; i++)
#pragma unroll
    for (int j = 0; j < 4; j++) acc[i][j] = floatx4{0.f, 0.f, 0.f, 0.f};

  for (int k0 = 0; k0 < K; k0 += 32) {
    stage_tile(As, pAh + k0, K, tid);
    if constexpr (SELB)
      stage_tile_sel(Bs, Bh, Bl, bm, n0, k0, K, tid);
    else
      stage_tile(Bs, pBh + k0, K, tid);
    if constexpr (SPLIT) {
      stage_tile(As + 4096, pAl + k0, K, tid);
      stage_tile(Bs + 4096, pBl + k0, K, tid);
    }
    __syncthreads();
    short8 afh[4], bfh[4];
#pragma unroll
    for (int i = 0; i < 4; i++)
      afh[i] = *(const short8*)&As[(wm + i * 16 + lm) * 32 + lq * 8];
#pragma unroll
    for (int i = 0; i < 4; i++)
      bfh[i] = *(const short8*)&Bs[(wn + i * 16 + lm) * 32 + lq * 8];
#pragma unroll
    for (int mi = 0; mi < 4; mi++)
#pragma unroll
      for (int ni = 0; ni < 4; ni++)
        acc[mi][ni] = __builtin_amdgcn_mfma_f32_16x16x32_bf16(afh[mi], bfh[ni], acc[mi][ni], 0, 0, 0);
    if constexpr (SPLIT) {
      {
        short8 afl[4];
#pragma unroll
        for (int i = 0; i < 4; i++)
          afl[i] = *(const short8*)&As[4096 + (wm + i * 16 + lm) * 32 + lq * 8];
#pragma unroll
        for (int mi = 0; mi < 4; mi++)
#pragma unroll
          for (int ni = 0; ni < 4; ni++)
            acc[mi][ni] = __builtin_amdgcn_mfma_f32_16x16x32_bf16(afl[mi], bfh[ni], acc[mi][ni], 0, 0, 0);
      }
      {
        short8 bfl[4];
#pragma unroll
        for (int i = 0; i < 4; i++)
          bfl[i] = *(const short8*)&Bs[4096 + (wn + i * 16 + lm) * 32 + lq * 8];
#pragma unroll
        for (int mi = 0; mi < 4; mi++)
#pragma unroll
          for (int ni = 0; ni < 4; ni++)
            acc[mi][ni] = __builtin_amdgcn_mfma_f32_16x16x32_bf16(afh[mi], bfl[ni], acc[mi][ni], 0, 0, 0);
      }
    }
    __syncthreads();
  }

  if constexpr (EPI == EPI_SILU) {
    ushort* o = (ushort*)outp + (size_t)z * o_bs;
    const float* bb = bias + (size_t)z * bias_bs;
#pragma unroll
    for (int mi = 0; mi < 4; mi++)
#pragma unroll
      for (int ni = 0; ni < 4; ni++) {
        int gm = m0 + wm + mi * 16 + lq * 4;
        int gn = n0 + wn + ni * 16 + lm;
        float bnv = bb[gn];
#pragma unroll
        for (int r = 0; r < 4; r++) {
          float v = acc[mi][ni][r] + bnv;
          float s = v / (1.f + __expf(-v));
          o[(size_t)(gm + r) * N + gn] = f2bf(s);
        }
      }
  } else if constexpr (EPI == EPI_F32) {
    float* o = (float*)outp;
#pragma unroll
    for (int mi = 0; mi < 4; mi++)
#pragma unroll
      for (int ni = 0; ni < 4; ni++) {
        int gm = m0 + wm + mi * 16 + lq * 4;
        int gn = n0 + wn + ni * 16 + lm;
        float bnv = bias[gn];
#pragma unroll
        for (int r = 0; r < 4; r++)
          o[(size_t)(gm + r) * N + gn] = acc[mi][ni][r] + bnv;
      }
  }
}

// ================= NEW: 256^2 8-wave split GEMM, 5-phase counted-vmcnt =================
// BM=BN=256, BK=32, 512 thr (8 waves, 2Mx4N), per-wave 128x64 out (acc[8][4]).
// LDS: 2 dbuf x 4 subtiles (Ah,Bh,Al,Bl) x 16KB = 128 KiB.
// Subtile layout: 256 rows x 32 bf16, 16B slot s of row r swizzled: s ^= (r>>1)&3
//   -> ds_read_b128 fragment reads are 2-way (free); write side stays linear for
//      global_load_lds by pre-swizzling the per-lane GLOBAL source (rule #21).
// Phases/K-step: P1top, P1bot, P3top(Al*Bh), P3bot, P2both(Ah*Bl); 16/16/16/16/32 MFMA.
// Counted vmcnt: Al ready via vmcnt(6) @ph2-end, Bl via vmcnt(8) @ph4-end,
// next Ah/Bh via vmcnt(4) @ph5-end. Tail iter: 2/0/- (drain).
#define LGKM0 do { asm volatile("s_waitcnt lgkmcnt(0)" ::: "memory"); \
                   __builtin_amdgcn_sched_barrier(0); } while (0)

__device__ __forceinline__ short8 fragld(const ushort* S, int r, int swz) {
  return *(const short8*)&S[r * 32 + swz];
}
__device__ __forceinline__ void stage256(ushort* d, const ushort* g,
                                         size_t soff0, size_t soff1, int dbase) {
  g2l(g + soff0, d + dbase);
  g2l(g + soff1, d + dbase + 4096);
}
__device__ __forceinline__ void mfma_block(floatx4 (&acc)[8][4], const short8 (&af)[4],
                                           int mi0, const short8 (&bf)[4]) {
#pragma unroll
  for (int mi = 0; mi < 4; mi++)
#pragma unroll
    for (int ni = 0; ni < 4; ni++)
      acc[mi0 + mi][ni] =
          __builtin_amdgcn_mfma_f32_16x16x32_bf16(af[mi], bf[ni], acc[mi0 + mi][ni], 0, 0, 0);
}

template <bool ST>
__device__ __forceinline__ void kstep256(
    floatx4 (&acc)[8][4], ushort (&lds)[2][4][8192], int p,
    const ushort* nA0, const ushort* nB0, const ushort* nA1, const ushort* nB1,
    size_t soff0, size_t soff1, int dbase, int swz, int lm, int wrow, int wcol) {
  const ushort* AhS = &lds[p][0][0];
  const ushort* BhS = &lds[p][1][0];
  const ushort* AlS = &lds[p][2][0];
  const ushort* BlS = &lds[p][3][0];
  ushort* dA0 = &lds[p ^ 1][0][0];
  ushort* dB0 = &lds[p ^ 1][1][0];
  ushort* dA1 = &lds[p ^ 1][2][0];
  ushort* dB1 = &lds[p ^ 1][3][0];

  short8 afh0[4], afh1[4], bfh[4];
  // ---- ph1: P1 top (Ah*Bh, mi 0..3)
#pragma unroll
  for (int i = 0; i < 4; i++) afh0[i] = fragld(AhS, wrow + i * 16 + lm, swz);
#pragma unroll
  for (int i = 0; i < 4; i++) bfh[i] = fragld(BhS, wcol + i * 16 + lm, swz);
  if constexpr (ST) stage256(dA0, nA0, soff0, soff1, dbase);
  __builtin_amdgcn_s_barrier();
  LGKM0;
  __builtin_amdgcn_s_setprio(1);
  mfma_block(acc, afh0, 0, bfh);
  __builtin_amdgcn_s_setprio(0);
  __builtin_amdgcn_s_barrier();
  // ---- ph2: P1 bottom (mi 4..7)
#pragma unroll
  for (int i = 0; i < 4; i++) afh1[i] = fragld(AhS, wrow + 64 + i * 16 + lm, swz);
  if constexpr (ST) stage256(dB0, nB0, soff0, soff1, dbase);
  __builtin_amdgcn_s_barrier();
  LGKM0;
  __builtin_amdgcn_s_setprio(1);
  mfma_block(acc, afh1, 4, bfh);
  __builtin_amdgcn_s_setprio(0);
  if constexpr (ST) asm volatile("s_waitcnt vmcnt(6)" ::: "memory");
  else              asm volatile("s_waitcnt vmcnt(2)" ::: "memory");
  __builtin_amdgcn_s_barrier();
  // ---- ph3: P3 top (Al*Bh)
  {
    short8 afl[4];
#pragma unroll
    for (int i = 0; i < 4; i++) afl[i] = fragld(AlS, wrow + i * 16 + lm, swz);
    if constexpr (ST) stage256(dA1, nA1, soff0, soff1, dbase);
    __builtin_amdgcn_s_barrier();
    LGKM0;
    __builtin_amdgcn_s_setprio(1);
    mfma_block(acc, afl, 0, bfh);
    __builtin_amdgcn_s_setprio(0);
    __builtin_amdgcn_s_barrier();
  }
  // ---- ph4: P3 bottom
  {
    short8 afl[4];
#pragma unroll
    for (int i = 0; i < 4; i++) afl[i] = fragld(AlS, wrow + 64 + i * 16 + lm, swz);
    if constexpr (ST) stage256(dB1, nB1, soff0, soff1, dbase);
    __builtin_amdgcn_s_barrier();
    LGKM0;
    __builtin_amdgcn_s_setprio(1);
    mfma_block(acc, afl, 4, bfh);
    __builtin_amdgcn_s_setprio(0);
    if constexpr (ST) asm volatile("s_waitcnt vmcnt(8)" ::: "memory");
    else              asm volatile("s_waitcnt vmcnt(0)" ::: "memory");
    __builtin_amdgcn_s_barrier();
  }
  // ---- ph5: P2 both halves (Ah*Bl)
  {
    short8 bfl[4];
#pragma unroll
    for (int i = 0; i < 4; i++) bfl[i] = fragld(BlS, wcol + i * 16 + lm, swz);
    __builtin_amdgcn_s_barrier();
    LGKM0;
    __builtin_amdgcn_s_setprio(1);
    mfma_block(acc, afh0, 0, bfl);
    mfma_block(acc, afh1, 4, bfl);
    __builtin_amdgcn_s_setprio(0);
    if constexpr (ST) asm volatile("s_waitcnt vmcnt(4)" ::: "memory");
    __builtin_amdgcn_s_barrier();
  }
}

template <int EPI>
__global__ __launch_bounds__(512, 2) void gemm256(
    const ushort* __restrict__ Ah, const ushort* __restrict__ Al,
    const ushort* __restrict__ Bh, const ushort* __restrict__ Bl,
    int N, int K, const float* __restrict__ bias,
    ushort* __restrict__ outh, ushort* __restrict__ outl,
    uint32* __restrict__ hist, uint32* __restrict__ hmax,
    uint32* __restrict__ buf, uint32* __restrict__ cnt) {
  static_assert(EPI == EPI_RELU || EPI == EPI_SCORE, "gemm256 handles G1/G2 only");
  __shared__ __align__(16) ushort lds[2][4][8192];   // 128 KiB
  const int tid = threadIdx.x;
  const int l = tid & 63, w = tid >> 6;
  const int lm = l & 15, lq = l >> 4;
  const int swz = (lq ^ ((lm >> 1) & 3)) << 3;       // read-side swizzled 16B slot (ushorts)
  const int wrow = (w >> 2) << 7, wcol = (w & 3) << 6;
  const int m0 = blockIdx.y << 8, n0 = blockIdx.x << 8;

  // staging: lane covers 16B-slot o = w*64+l (and +512); row=o>>2, col-group pre-swizzled
  const int cg = ((l & 3) ^ ((l >> 3) & 3)) << 3;    // source col offset (ushorts)
  const int r0 = (w << 4) + (l >> 2);
  const size_t soff0 = (size_t)r0 * K + cg;
  const size_t soff1 = soff0 + (size_t)128 * K;
  const int dbase = w << 9;                          // wave-uniform LDS dest (ushorts)

  const ushort* pA0 = Ah + (size_t)m0 * K;
  const ushort* pA1 = Al + (size_t)m0 * K;
  const ushort* pB0 = Bh + (size_t)n0 * K;
  const ushort* pB1 = Bl + (size_t)n0 * K;

  floatx4 acc[8][4];
#pragma unroll
  for (int i = 0; i < 8; i++)
#pragma unroll
    for (int j = 0; j < 4; j++) acc[i][j] = floatx4{0.f, 0.f, 0.f, 0.f};

  // prologue: stage step0 fully; wait Ah0/Bh0 only (Al0/Bl0 stay in flight)
  stage256(&lds[0][0][0], pA0, soff0, soff1, dbase);
  stage256(&lds[0][1][0], pB0, soff0, soff1, dbase);
  stage256(&lds[0][2][0], pA1, soff0, soff1, dbase);
  stage256(&lds[0][3][0], pB1, soff0, soff1, dbase);
  asm volatile("s_waitcnt vmcnt(4)" ::: "memory");
  __builtin_amdgcn_s_barrier();

  const int nk = K >> 5;   // nk >= 2 always here
  int T = 0;
  for (; T < nk - 1; ++T) {
    const int ko = (T + 1) << 5;
    kstep256<true>(acc, lds, T & 1, pA0 + ko, pB0 + ko, pA1 + ko, pB1 + ko,
                   soff0, soff1, dbase, swz, lm, wrow, wcol);
  }
  kstep256<false>(acc, lds, T & 1, pA0, pB0, pA1, pB1,
                  soff0, soff1, dbase, swz, lm, wrow, wcol);

  // ---- epilogue. D layout: row = wrow+mi*16+lq*4+r, col = wcol+ni*16+lm (m89/m91) ----
  if constexpr (EPI == EPI_RELU) {
#pragma unroll
    for (int mi = 0; mi < 8; mi++)
#pragma unroll
      for (int ni = 0; ni < 4; ni++) {
        const int gm = m0 + wrow + mi * 16 + lq * 4;
        const int gn = n0 + wcol + ni * 16 + lm;
        const float bnv = bias[gn];
#pragma unroll
        for (int r = 0; r < 4; r++) {
          float v = fmaxf(acc[mi][ni][r] + bnv, 0.f);
          ushort h = f2bf(v);
          size_t o = (size_t)(gm + r) * N + gn;
          outh[o] = h;
          outl[o] = f2bf(v - bf2f(h));
        }
      }
  } else {  // EPI_SCORE
    __syncthreads();
    uint32* hs = (uint32*)&lds[0][0][0];
    for (int i = tid; i < 8192; i += 512) hs[i] = 0;
    __syncthreads();
    const int batch = m0 >> 10;  // 256-row blocks never straddle a batch
    uint32 cntl = 0;
#pragma unroll
    for (int ni = 0; ni < 4; ni++) {
      const int gn = n0 + wcol + ni * 16 + lm;
      const float bnv = bias[gn];
      float vmax = -3.4e38f;
#pragma unroll
      for (int mi = 0; mi < 8; mi++) {
#pragma unroll
        for (int r = 0; r < 4; r++) {
          float v = acc[mi][ni][r] + bnv;
          uint32 e = ekey(skey(v));
          uint32 bk = e >> 14;
          atomicAdd(&hs[bk], 1u);
          if (bk >= WLO && bk <= WHI) cntl++;
          vmax = fmaxf(vmax, v);
        }
      }
      atomicMax(&hmax[batch * Hn + gn], skey(vmax));
    }
    __syncthreads();
    for (int i = tid; i < 8192; i += 512) {
      uint32 c = hs[i];
      if (c) atomicAdd(&hist[batch * 8192 + i], c);
    }
    __syncthreads();
    hs[tid] = cntl;
    __syncthreads();
    if (tid == 0) {
      uint32 run = 0;
      for (int i = 0; i < 512; i++) { uint32 t = hs[i]; hs[i] = run; run += t; }
      hs[512] = atomicAdd(&cnt[batch], run);
    }
    __syncthreads();
    uint32 off = hs[512] + hs[tid];
    uint32* bb = buf + (size_t)batch * CAP;
#pragma unroll
    for (int ni = 0; ni < 4; ni++) {
      const int gn = n0 + wcol + ni * 16 + lm;
      const float bnv = bias[gn];
#pragma unroll
      for (int mi = 0; mi < 8; mi++) {
#pragma unroll
        for (int r = 0; r < 4; r++) {
          float v = acc[mi][ni][r] + bnv;
          uint32 e = ekey(skey(v));
          uint32 bk = e >> 14;
          if (bk >= WLO && bk <= WHI) {
            if (off < CAP) bb[off] = e;
            off++;
          }
        }
      }
    }
  }
}

// ---------------- selection kernels ----------------
__global__ __launch_bounds__(256) void select1_k(const uint32* __restrict__ hist,
                                                 uint32* __restrict__ meta) {
  int b = blockIdx.x;
  const uint32* h = hist + b * 8192;
  __shared__ uint32 ps[256];
  uint32 s = 0;
  int base = threadIdx.x * 32;
  for (int i = 0; i < 32; i++) s += h[base + i];
  ps[threadIdx.x] = s;
  __syncthreads();
  if (threadIdx.x == 0) {
    uint32 cum = 0, need = 1;
    int j = 0;
    for (int c = 255; c >= 0; c--) {
      if (cum + ps[c] >= KTOP) {
        for (int i = c * 32 + 31;; i--) {
          uint32 hv = h[i];
          if (cum + hv >= KTOP) { j = i; need = KTOP - cum; break; }
          cum += hv;
        }
        break;
      }
      cum += ps[c];
    }
    meta[8 + b] = (uint32)j;
    meta[16 + b] = need;
    meta[b] = SKBASE + ((uint32)j << 14);
  }
}

__global__ __launch_bounds__(256) void refine_buf_k(const uint32* __restrict__ buf,
                                                    const uint32* __restrict__ meta,
                                                    uint32* __restrict__ hist2) {
  const uint32* cnt = meta + 32;
  size_t stride = (size_t)gridDim.x * 256;
  for (int b = 0; b < Bn; b++) {
    uint32 n = cnt[b] < CAP ? cnt[b] : CAP;
    uint32 j = meta[8 + b];
    const uint32* bb = buf + (size_t)b * CAP;
    for (size_t i = (size_t)blockIdx.x * 256 + threadIdx.x; i < n; i += stride) {
      uint32 e = bb[i];
      if ((e >> 14) == j) atomicAdd(&hist2[(size_t)b * 16384 + (e & 0x3FFFu)], 1u);
    }
  }
}

__global__ __launch_bounds__(256) void select2_k(const uint32* __restrict__ hist2,
                                                 uint32* __restrict__ meta) {
  int b = blockIdx.x;
  const uint32* h2 = hist2 + (size_t)b * 16384;
  __shared__ uint32 ps[256];
  uint32 s = 0;
  const uint32* p = h2 + (size_t)threadIdx.x * 64;
  for (int i = 0; i < 64; i += 4) {
    uint4 v = *(const uint4*)(p + i);
    s += v.x + v.y + v.z + v.w;
  }
  ps[threadIdx.x] = s;
  __syncthreads();
  if (threadIdx.x == 0) {
    uint32 j = meta[8 + b];
    uint32 valid = (j >= WLO && j <= WHI && meta[32 + b] <= CAP) ? 1u : 0u;
    if (valid) {
      uint32 need = meta[16 + b];
      uint32 cum = 0;
      int c = 255;
      for (; c > 0; c--) {
        if (cum + ps[c] >= need) break;
        cum += ps[c];
      }
      uint32 rem = 0;
      for (int i = 63; i >= 0; i--) {
        uint32 hv = h2[c * 64 + i];
        if (cum + hv >= need) { rem = (uint32)(c * 64 + i); break; }
        cum += hv;
      }
      meta[b] = SKBASE + (j << 14) + rem;
    }
  }
}

__global__ __launch_bounds__(256) void mask_k(const uint32* __restrict__ hmax,
                                              const uint32* __restrict__ meta,
                                              const float* __restrict__ modb,
                                              const float* __restrict__ upb,
                                              uint32* __restrict__ mask,
                                              float* __restrict__ bsel) {
  int i = blockIdx.x * 256 + threadIdx.x;  // Bn*Hn = 32768
  int b = i >> 12, h = i & 4095;
  bool m = hmax[i] >= meta[b];
  mask[i] = m ? 1u : 0u;
  bsel[i] = m ? modb[h] : upb[h];
}

// ---------------- launch ----------------
extern "C" void kernel_launch(void* const* d_in, const int* in_sizes, int n_in,
                              void* d_out, int out_size, void* d_ws, size_t ws_size,
                              hipStream_t stream) {
  (void)in_sizes; (void)n_in;
  const float* x    = (const float*)d_in[0];
  const float* up_w = (const float*)d_in[1];
  const float* up_b = (const float*)d_in[2];
  const float* g_w1 = (const float*)d_in[3];
  const float* g_b1 = (const float*)d_in[4];
  const float* g_w2 = (const float*)d_in[5];
  const float* g_b2 = (const float*)d_in[6];
  const float* mod_w= (const float*)d_in[7];
  const float* mod_b= (const float*)d_in[8];
  const float* dw   = (const float*)d_in[9];
  const float* db   = (const float*)d_in[10];
  float* out = (float*)d_out;

  if (ws_size < WS_SMALL) {
    zero_out_k<<<(out_size + 255) / 256, 256, 0, stream>>>(out, out_size);
    return;
  }

  char* ws = (char*)d_ws;
  ushort* XH  = (ushort*)(ws + OFF_XH);
  ushort* XL  = (ushort*)(ws + OFF_XL);
  ushort* W1H = (ushort*)(ws + OFF_W1H);
  ushort* W1L = (ushort*)(ws + OFF_W1L);
  ushort* W2H = (ushort*)(ws + OFF_W2H);
  ushort* W2L = (ushort*)(ws + OFF_W2L);
  ushort* RSH = (ushort*)(ws + OFF_RSH);
  ushort* RSL = (ushort*)(ws + OFF_RSL);
  uint32* HIST = (uint32*)(ws + OFF_HIST);
  uint32* HIST2= (uint32*)(ws + OFF_HIST2);
  uint32* HMAX = (uint32*)(ws + OFF_HMAX);
  uint32* META = (uint32*)(ws + OFF_META);
  float*  BSEL = (float*)(ws + OFF_BSEL);
  uint32* MASK = (uint32*)(ws + OFF_MASK);
  uint32* BUF  = (uint32*)(ws + OFF_BUF);
  ushort* UPW  = W1H;
  ushort* MODW = W1L;
  ushort* DWNW = XL;
  ushort* HBUF = RSH;

  hipMemsetAsync(ws + OFF_HIST, 0, ZERO_BYTES, stream);

  cvt_split_k<<<1024, 256, 0, stream>>>((const float4*)x, XH, XL, (int)(NX / 4));
  cvt_split_k<<<1024, 256, 0, stream>>>((const float4*)g_w1, W1H, W1L, (int)(NW1 / 4));
  cvt_split_k<<<2048, 256, 0, stream>>>((const float4*)g_w2, W2H, W2L, (int)(NW2 / 4));

  // G1: rs = relu(X*W1^T + b1), split-bf16, split store — NEW 256^2 5-phase kernel
  gemm256<EPI_RELU><<<dim3(Hn / 256, (Bn * Sn) / 256), 512, 0, stream>>>(
      XH, XL, W1H, W1L, Hn, Dn, g_b1, RSH, RSL, nullptr, nullptr, nullptr, nullptr);
  // G2: scores = rs*W2^T + b2; fused hist/colmax + windowed key append — NEW kernel
  gemm256<EPI_SCORE><<<dim3(Hn / 256, (Bn * Sn) / 256), 512, 0, stream>>>(
      RSH, RSL, W2H, W2L, Hn, Hn, g_b2, nullptr, nullptr, HIST, HMAX, BUF, META + 32);

  select1_k<<<Bn, 256, 0, stream>>>(HIST, META);
  refine_buf_k<<<512, 256, 0, stream>>>(BUF, META, HIST2);
  select2_k<<<Bn, 256, 0, stream>>>(HIST2, META);
  mask_k<<<(Bn * Hn) / 256, 256, 0, stream>>>(HMAX, META, mod_b, up_b, MASK, BSEL);

  cvt_single_k<<<1024, 256, 0, stream>>>((const float4*)up_w, UPW, (int)(NW1 / 4));
  cvt_single_k<<<1024, 256, 0, stream>>>((const float4*)mod_w, MODW, (int)(NW1 / 4));
  cvt_single_k<<<1024, 256, 0, stream>>>((const float4*)dw, DWNW, (int)(NW1 / 4));

  // G3: h = silu(X * sel_w^T + sel_b), B rows selected per-lane at staging time
  gemm_bt<false, true, EPI_SILU><<<dim3(Hn / 128, Sn / 128, Bn), 256, 0, stream>>>(
      XH, nullptr, UPW, MODW, MASK, Hn, Dn,
      (long long)Sn * Dn, (long long)Sn * Hn, (long long)Hn,
      BSEL, HBUF, nullptr, nullptr, nullptr, nullptr, nullptr);
  // G4: out = h * down_w^T + down_b (fp32 out)
  gemm_bt<false, false, EPI_F32><<<dim3(Dn / 128, (Bn * Sn) / 128, 1), 256, 0, stream>>>(
      HBUF, nullptr, DWNW, nullptr, nullptr, Dn, Hn, 0, 0, 0, db, out, nullptr,
      nullptr, nullptr, nullptr, nullptr);
}